// Round 19
// baseline (264.304 us; speedup 1.0000x reference)
//
#include <hip/hip_runtime.h>

#define NB 32
#define NGT 100
#define NL 8400
#define NC 80
#define KTOP 13
#define MAXC 640  // >= max enumerated candidates per (b,n) (bound ~531)
#define NROWS (NB * NL)          // 268800
#define TK_BLOCKS (NB * NGT / 4) // 800 topk blocks (4 waves each)
#define F_BLOCKS 2048            // background F-pass blocks
#define TOTAL4 ((unsigned)NROWS * 20)  // 5,376,000 float4 units of ps
#define BT 1024                  // batch_kernel threads
#define NCHUNK ((NL + BT - 1) / BT)    // 9
#define LN2F 0.6931471805599453f

__device__ __forceinline__ float clamp0(float x) { return fmaxf(x, 0.f); }

__device__ __forceinline__ unsigned long long mkkey(float v, unsigned lowk) {
  return ((unsigned long long)__float_as_uint(v) << 32) | (unsigned long long)lowk;
}

// background per-element class-loss term f(s) = -log1p(-s)*0.75*s^2
__device__ __forceinline__ float fbg(float s) {
  float pcl = fminf(fmaxf(s, 1e-9f), 1.f - 1e-9f);
  float lp1 = __log2f(1.f - pcl) * LN2F;
  return -lp1 * 0.75f * s * s;
}

// anchor center coords from flat index l (bit-exact vs numpy setup)
__device__ __forceinline__ void anchor_xy(int l, float& x, float& y) {
  if (l < 6400)      { int rr = l / 80, cc = l - rr * 80;
                       x = ((float)cc + 0.5f) * 8.f;  y = ((float)rr + 0.5f) * 8.f; }
  else if (l < 8000) { int id = l - 6400; int rr = id / 40, cc = id - rr * 40;
                       x = ((float)cc + 0.5f) * 16.f; y = ((float)rr + 0.5f) * 16.f; }
  else               { int id = l - 8000; int rr = id / 20, cc = id - rr * 20;
                       x = ((float)cc + 0.5f) * 32.f; y = ((float)rr + 0.5f) * 32.f; }
}

// Block-reduce a double (256 threads, 4 waves); result valid on thread 0.
__device__ __forceinline__ double block_red(double v, double* sred) {
  for (int off = 32; off > 0; off >>= 1) v += __shfl_down(v, off);
  int wid = threadIdx.x >> 6;
  if ((threadIdx.x & 63) == 0) sred[wid] = v;
  __syncthreads();
  double r = 0.0;
  if (threadIdx.x == 0) r = sred[0] + sred[1] + sred[2] + sred[3];
  __syncthreads();
  return r;
}

// Block-reduce a double (1024 threads, 16 waves); result valid on thread 0.
__device__ __forceinline__ double block_red16(double v, double* sred) {
  for (int off = 32; off > 0; off >>= 1) v += __shfl_down(v, off);
  int wid = threadIdx.x >> 6;
  if ((threadIdx.x & 63) == 0) sred[wid] = v;
  __syncthreads();
  double r = 0.0;
  if (threadIdx.x == 0)
    for (int i = 0; i < 16; ++i) r += sred[i];
  __syncthreads();
  return r;
}

// conservative grid range for centers (c+0.5)*s inside (lo, hi)
__device__ __forceinline__ void grange(float lo, float hi, float s, int G,
                                       int& a0, int& an) {
  int c0 = max(0, (int)floorf(lo / s - 0.5f));
  int c1 = min(G - 1, (int)ceilf(hi / s - 0.5f));
  a0 = c0;
  an = max(0, c1 - c0 + 1);
}

// ---- Node 1: blocks 0..799 = wave-per-(b,n) topk (zero barriers);
// ----         blocks 800..  = background F-pass over ps (streaming).
__global__ __launch_bounds__(256) void combo_kernel(
    const float* __restrict__ ps, const float* __restrict__ pb,
    const int* __restrict__ gl, const float* __restrict__ gtb,
    int* __restrict__ topk_out, double* __restrict__ partF)
{
  __shared__ unsigned long long cand[4][MAXC];
  __shared__ int cnt[4];
  __shared__ double sred[4];

  if (blockIdx.x >= TK_BLOCKS) {
    // ---------------- F-pass: pure streaming background sum ----------------
    const int fb = blockIdx.x - TK_BLOCKS;
    const float4* ps4 = (const float4*)ps;
    double acc = 0.0;
    for (unsigned gid = (unsigned)fb * 256 + threadIdx.x; gid < TOTAL4;
         gid += (unsigned)F_BLOCKS * 256) {
      float4 s4 = ps4[gid];
      acc += (double)(fbg(s4.x) + fbg(s4.y) + fbg(s4.z) + fbg(s4.w));
    }
    double r = block_red(acc, sred);
    if (threadIdx.x == 0) partF[fb] = r;
    return;
  }

  // --------------------------- topk branch ---------------------------------
  const int wid = (int)(threadIdx.x >> 6);
  const int lane = (int)(threadIdx.x & 63);
  const int bn = blockIdx.x * 4 + wid;
  const int b = bn / NGT;
  const float gx1 = gtb[bn * 4 + 0], gy1 = gtb[bn * 4 + 1];
  const float gx2 = gtb[bn * 4 + 2], gy2 = gtb[bn * 4 + 3];
  const int cls = gl[bn];
  const float ga = clamp0(gx2 - gx1) * clamp0(gy2 - gy1);
  const float4* pbb = (const float4*)pb + (size_t)b * NL;
  const float* psb = ps + (size_t)b * NL * NC;

  if (lane == 0) cnt[wid] = 0;

  // Pass A: zero-metric mask for anchors 0..63 (row 0 of s8 grid), in-wave.
  unsigned long long zm;
  {
    const int l = lane;
    float4 p = pbb[l];
    float x = ((float)l + 0.5f) * 8.0f, y = 4.0f;
    float ox = fminf(p.z, gx2) - fmaxf(p.x, gx1);
    float oy = fminf(p.w, gy2) - fmaxf(p.y, gy1);
    float ov = clamp0(ox) * clamp0(oy);
    float pa = clamp0(p.z - p.x) * clamp0(p.w - p.y);
    float iou = ov * __builtin_amdgcn_rcpf(ga + pa - ov + 1e-9f);
    bool ins = fminf(fminf(x - gx1, y - gy1),
                     fminf(gx2 - x, gy2 - y)) > 1e-9f;
    bool pos = ins && (iou > 0.f);
    zm = __ballot(!pos);  // uniform across the wave
  }

  // Candidate windows per scale (identical scalars on all lanes).
  int c8, nc8, r8, nr8, c16, nc16, r16, nr16, c32, nc32, r32, nr32;
  grange(gx1, gx2, 8.f, 80, c8, nc8);   grange(gy1, gy2, 8.f, 80, r8, nr8);
  grange(gx1, gx2, 16.f, 40, c16, nc16); grange(gy1, gy2, 16.f, 40, r16, nr16);
  grange(gx1, gx2, 32.f, 20, c32, nc32); grange(gy1, gy2, 32.f, 20, r32, nr32);
  const int t8 = nc8 * nr8, t16 = nc16 * nr16, t32 = nc32 * nr32;
  const int total = t8 + t16 + t32;

  // Phase 1: test enumerated candidates; positives -> this wave's LDS list.
  for (int idx = lane; idx < total; idx += 64) {
    int l; float x, y;
    if (idx < t8) {
      int q = idx / nc8, cc = c8 + (idx - q * nc8), rr = r8 + q;
      l = rr * 80 + cc; x = ((float)cc + 0.5f) * 8.f; y = ((float)rr + 0.5f) * 8.f;
    } else if (idx < t8 + t16) {
      int id = idx - t8;
      int q = id / nc16, cc = c16 + (id - q * nc16), rr = r16 + q;
      l = 6400 + rr * 40 + cc; x = ((float)cc + 0.5f) * 16.f; y = ((float)rr + 0.5f) * 16.f;
    } else {
      int id = idx - t8 - t16;
      int q = id / nc32, cc = c32 + (id - q * nc32), rr = r32 + q;
      l = 8000 + rr * 20 + cc; x = ((float)cc + 0.5f) * 32.f; y = ((float)rr + 0.5f) * 32.f;
    }
    float4 p = pbb[l];
    float ox = fminf(p.z, gx2) - fmaxf(p.x, gx1);
    float oy = fminf(p.w, gy2) - fmaxf(p.y, gy1);
    float ov = clamp0(ox) * clamp0(oy);
    float pa = clamp0(p.z - p.x) * clamp0(p.w - p.y);
    float iou = ov * __builtin_amdgcn_rcpf(ga + pa - ov + 1e-9f);
    bool ins = fminf(fminf(x - gx1, y - gy1),
                     fminf(gx2 - x, gy2 - y)) > 1e-9f;
    if (ins && iou > 0.f) {
      int id2 = atomicAdd(&cnt[wid], 1);
      if (id2 < MAXC)
        cand[wid][id2] = ((unsigned long long)__float_as_uint(iou) << 32) |
                         (unsigned long long)(0xFFFFFFFFu - (unsigned)l);
    }
  }

  // Phase 2: gather score for positives; finalize key v = sc * iou^6.
  const int n = min(cnt[wid], MAXC);   // uniform per wave
  unsigned long long zadd = 0ull;
  for (int idx = lane; idx < n; idx += 64) {
    unsigned long long e = cand[wid][idx];
    unsigned lowk = (unsigned)e;
    int l = (int)(0xFFFFFFFFu - lowk);
    float iou = __uint_as_float((unsigned)(e >> 32));
    float sc = psb[(size_t)l * NC + cls];
    float i2 = iou * iou;
    float v = sc * i2 * i2 * i2;
    if (v > 0.f) {
      cand[wid][idx] = mkkey(v, lowk);
    } else {               // underflow: metric exactly 0 -> zero-tie set
      cand[wid][idx] = 0ull;
      if (l < 64) zadd |= (1ull << l);
    }
  }
  for (int off = 1; off < 64; off <<= 1)
    zadd |= __shfl_xor(zadd, off);
  zm |= zadd;              // still uniform

  // Merge: 13 rounds of pure-shuffle wave max; lanes hold <=10 candidates.
  unsigned long long c[MAXC / 64];
#pragma unroll
  for (int j = 0; j < MAXC / 64; ++j) {
    int idx = lane + 64 * j;
    c[j] = (idx < n) ? cand[wid][idx] : 0ull;
  }
  for (int k = 0; k < KTOP; ++k) {
    unsigned long long m = c[0];
#pragma unroll
    for (int j = 1; j < MAXC / 64; ++j) m = (c[j] > m) ? c[j] : m;
    for (int off = 1; off < 64; off <<= 1) {
      unsigned long long o = __shfl_xor(m, off);
      m = (o > m) ? o : m;
    }
    int outl;
    if (m != 0ull) {  // a positive candidate wins
#pragma unroll
      for (int j = 0; j < MAXC / 64; ++j)
        if (c[j] == m) c[j] = 0ull;
      outl = (int)(0xFFFFFFFFu - (unsigned)(m & 0xFFFFFFFFull));
    } else {          // pad with smallest-index zero-metric anchor
      outl = (int)(__ffsll((long long)zm) - 1);
      zm &= zm - 1;
    }
    if (lane == 0) topk_out[bn * KTOP + k] = outl;
  }
}

// ---- Node 2: BATCH-PER-BLOCK fused assign+correct -------------------------
// One 1024-thread block per batch. Assignment maxima (maxm/maxi) live in
// LDS (order-independent atomicMax -> deterministic); per-anchor ns/al_s in
// LDS; after a barrier the same block runs the correction phase with the
// finalized maxima. No global round-trip, no extra node, no fences.
__global__ __launch_bounds__(BT) void batch_kernel(
    const float* __restrict__ ps, const float* __restrict__ pb,
    const int* __restrict__ gl, const float* __restrict__ gtb,
    const float* __restrict__ pad, const int* __restrict__ topk,
    double* __restrict__ partB)
{
  __shared__ float4 sgt[NGT];
  __shared__ int sgl[NGT];
  __shared__ float spad[NGT];
  __shared__ unsigned smaxm[NGT], smaxi[NGT];
  __shared__ short sns[NL];
  __shared__ float sast[NL];
  __shared__ unsigned hitm[BT][4];
  __shared__ double sred[16];
  const int b = blockIdx.x;
  const float4* pbb = (const float4*)pb + (size_t)b * NL;
  const float* psb = ps + (size_t)b * NL * NC;

  for (int i = threadIdx.x; i < NGT; i += BT) {
    sgt[i] = ((const float4*)gtb)[b * NGT + i];
    sgl[i] = gl[b * NGT + i];
    spad[i] = pad[b * NGT + i];
    smaxm[i] = 0u;
    smaxi[i] = 0u;
  }
  __syncthreads();

  // ---------------- assignment phase, chunked over anchors ----------------
  for (int ch = 0; ch < NCHUNK; ++ch) {
    const int l0 = ch * BT;
    hitm[threadIdx.x][0] = 0u; hitm[threadIdx.x][1] = 0u;
    hitm[threadIdx.x][2] = 0u; hitm[threadIdx.x][3] = 0u;
    __syncthreads();

    // scatter: batch's 1300 topk entries -> hit bits for anchors in chunk
    for (int i = threadIdx.x; i < NGT * KTOP; i += BT) {
      const int n = i / KTOP;
      if (spad[n] == 0.f) continue;
      const int l = topk[b * NGT * KTOP + i];
      if (l < l0 || l >= l0 + BT || l >= NL) continue;
      float ax, ay;
      anchor_xy(l, ax, ay);
      float4 g = sgt[n];
      bool ins = fminf(fminf(ax - g.x, ay - g.y),
                       fminf(g.z - ax, g.w - ay)) > 1e-9f;
      if (ins) atomicOr(&hitm[l - l0][n >> 5], 1u << (n & 31));
    }
    __syncthreads();

    const int l = l0 + (int)threadIdx.x;
    if (l < NL) {
      const unsigned m0 = hitm[threadIdx.x][0], m1 = hitm[threadIdx.x][1];
      const unsigned m2 = hitm[threadIdx.x][2], m3 = hitm[threadIdx.x][3];
      const int mps = __popc(m0) + __popc(m1) + __popc(m2) + __popc(m3);
      int ns = -1;
      float iou_s = 0.f, al_s = 0.f;
      if (mps > 0) {
        float4 p = pbb[l];
        float pa = clamp0(p.z - p.x) * clamp0(p.w - p.y);
        if (mps == 1) {
          if (m0) ns = __ffs(m0) - 1;
          else if (m1) ns = 32 + __ffs(m1) - 1;
          else if (m2) ns = 64 + __ffs(m2) - 1;
          else ns = 96 + __ffs(m3) - 1;
          float4 g = sgt[ns];
          float ox = fminf(p.z, g.z) - fmaxf(p.x, g.x);
          float oy = fminf(p.w, g.w) - fmaxf(p.y, g.y);
          float ov = clamp0(ox) * clamp0(oy);
          float ga = clamp0(g.z - g.x) * clamp0(g.w - g.y);
          iou_s = ov / (ga + pa - ov + 1e-9f);   // exact: matches original
        } else {
          // is_max_iou: argmax over ALL n (incl. pad), first-max wins
          int max_n = 0; float max_iou = -1.f;
          for (int n = 0; n < NGT; ++n) {
            float4 g = sgt[n];
            float ox = fminf(p.z, g.z) - fmaxf(p.x, g.x);
            float oy = fminf(p.w, g.w) - fmaxf(p.y, g.y);
            float ov = clamp0(ox) * clamp0(oy);
            float ga = clamp0(g.z - g.x) * clamp0(g.w - g.y);
            float iou = ov / (ga + pa - ov + 1e-9f);
            if (iou > max_iou) { max_iou = iou; max_n = n; }
          }
          ns = max_n; iou_s = max_iou;
        }
        float sc = psb[(size_t)l * NC + sgl[ns]];
        float i2 = iou_s * iou_s;
        al_s = sc * i2 * i2 * i2;
        atomicMax(&smaxm[ns], __float_as_uint(al_s));
        atomicMax(&smaxi[ns], __float_as_uint(iou_s));
      }
      sns[l] = (short)ns;
      sast[l] = al_s;
    }
    __syncthreads();
  }

  // ---------------- correction phase (maxima now final) --------------------
  double csum = 0.0, gsum = 0.0, asum = 0.0;
  for (int l = threadIdx.x; l < NL; l += BT) {
    int ns = sns[l];
    if (ns < 0) continue;
    float mm = __uint_as_float(smaxm[ns]);
    float mi = __uint_as_float(smaxi[ns]);
    float scale = sast[l] / (mm + 1e-9f) * mi;
    int j = sgl[ns];
    asum += (double)scale;
    // class-loss correction at the assigned class
    float s = psb[(size_t)l * NC + j];
    float pcl = fminf(fmaxf(s, 1e-9f), 1.f - 1e-9f);
    float lp1 = __log2f(1.f - pcl) * LN2F;
    float lpp = __log2f(pcl) * LN2F;
    float term = -(scale * lpp + (1.f - scale) * lp1) * scale;
    float fsj = -lp1 * 0.75f * s * s;
    csum += (double)(term - fsj);
    // GIoU
    float4 p = pbb[l];
    float4 g = sgt[ns];
    float x1 = fmaxf(p.x, g.x), y1 = fmaxf(p.y, g.y);
    float x2 = fminf(p.z, g.z), y2 = fminf(p.w, g.w);
    float ov = clamp0(x2 - x1) * clamp0(y2 - y1);
    float pa = clamp0(p.z - p.x) * clamp0(p.w - p.y);
    float ga = clamp0(g.z - g.x) * clamp0(g.w - g.y);
    float un = pa + ga - ov + 1e-10f;
    float iou = ov / un;
    float cx1 = fminf(p.x, g.x), cy1 = fminf(p.y, g.y);
    float cx2 = fmaxf(p.z, g.z), cy2 = fmaxf(p.w, g.w);
    float cc = clamp0(cx2 - cx1) * clamp0(cy2 - cy1) + 1e-10f;
    float gi = 1.f - (iou - (cc - un) / cc);
    gsum += (double)(gi * scale);
  }
  double r0 = block_red16(csum, sred);
  double r1 = block_red16(gsum, sred);
  double r2 = block_red16(asum, sred);
  if (threadIdx.x == 0) {
    partB[(size_t)b * 4 + 0] = r0;
    partB[(size_t)b * 4 + 1] = r1;
    partB[(size_t)b * 4 + 2] = r2;
  }
}

// ---------------- Node 3: reduce partials, emit scalar ---------------------
__global__ __launch_bounds__(256) void fin_kernel(
    const double* __restrict__ partF, const double* __restrict__ partB,
    float* __restrict__ out)
{
  __shared__ double sred[4];
  double c = 0.0, g = 0.0, a = 0.0;
  for (int i = threadIdx.x; i < F_BLOCKS; i += 256) c += partF[i];
  if (threadIdx.x < NB) {
    c += partB[(size_t)threadIdx.x * 4 + 0];
    g += partB[(size_t)threadIdx.x * 4 + 1];
    a += partB[(size_t)threadIdx.x * 4 + 2];
  }
  c = block_red(c, sred);
  g = block_red(g, sred);
  a = block_red(a, sred);
  if (threadIdx.x == 0) {
    double s = a > 1.0 ? a : 1.0;
    out[0] = (float)((c + 2.5 * g) / s);
  }
}

// ---------------------------------------------------------------------------
extern "C" void kernel_launch(void* const* d_in, const int* in_sizes, int n_in,
                              void* d_out, int out_size, void* d_ws, size_t ws_size,
                              hipStream_t stream) {
  const float* ps  = (const float*)d_in[0];   // [32,8400,80]
  const float* pbx = (const float*)d_in[1];   // [32,8400,4]
  const float* ap  = (const float*)d_in[2];   // [8400,2] (unused: grid math)
  const int*   gl  = (const int*)d_in[3];     // [32,100,1]
  const float* gtb = (const float*)d_in[4];   // [32,100,4]
  const float* pad = (const float*)d_in[5];   // [32,100,1]
  (void)ap;

  char* ws = (char*)d_ws;
  const size_t OFF_TOPK  = 0;                                 // 41600 i32
  const size_t OFF_PARTF = OFF_TOPK + 4ul * NB * NGT * KTOP;  // 2048 f64
  const size_t OFF_PARTB = OFF_PARTF + 8ul * F_BLOCKS;        // 32*4 f64

  int*      topk  = (int*)(ws + OFF_TOPK);
  double*   partF = (double*)(ws + OFF_PARTF);
  double*   partB = (double*)(ws + OFF_PARTB);

  hipLaunchKernelGGL(combo_kernel, dim3(TK_BLOCKS + F_BLOCKS), dim3(256), 0,
                     stream, ps, pbx, gl, gtb, topk, partF);
  hipLaunchKernelGGL(batch_kernel, dim3(NB), dim3(BT), 0, stream,
                     ps, pbx, gl, gtb, pad, topk, partB);
  hipLaunchKernelGGL(fin_kernel, dim3(1), dim3(256), 0, stream, partF, partB,
                     (float*)d_out);
}

// Round 20
// 67.645 us; speedup vs baseline: 3.9072x; 3.9072x over previous
//
#include <hip/hip_runtime.h>

#define NB 32
#define NGT 100
#define NL 8400
#define NC 80
#define KTOP 13
#define MAXC 640  // >= max enumerated candidates per (b,n) (bound ~531)
#define NROWS (NB * NL)          // 268800
#define TK_BLOCKS (NB * NGT / 4) // 800 topk blocks (4 waves each)
#define F_BLOCKS 2048            // background F-pass blocks
#define CR_BLOCKS (NROWS / 256)  // 1050 correction blocks
#define SC_BLOCKS_X 33           // ceil(8400/256)
#define TOTAL4 ((unsigned)NROWS * 20)  // 5,376,000 float4 units of ps
#define LN2F 0.6931471805599453f

__device__ __forceinline__ float clamp0(float x) { return fmaxf(x, 0.f); }

__device__ __forceinline__ unsigned long long mkkey(float v, unsigned lowk) {
  return ((unsigned long long)__float_as_uint(v) << 32) | (unsigned long long)lowk;
}

// background per-element class-loss term f(s) = -log1p(-s)*0.75*s^2
__device__ __forceinline__ float fbg(float s) {
  float pcl = fminf(fmaxf(s, 1e-9f), 1.f - 1e-9f);
  float lp1 = __log2f(1.f - pcl) * LN2F;
  return -lp1 * 0.75f * s * s;
}

// anchor center coords from flat index l (bit-exact vs numpy setup)
__device__ __forceinline__ void anchor_xy(int l, float& x, float& y) {
  if (l < 6400)      { int rr = l / 80, cc = l - rr * 80;
                       x = ((float)cc + 0.5f) * 8.f;  y = ((float)rr + 0.5f) * 8.f; }
  else if (l < 8000) { int id = l - 6400; int rr = id / 40, cc = id - rr * 40;
                       x = ((float)cc + 0.5f) * 16.f; y = ((float)rr + 0.5f) * 16.f; }
  else               { int id = l - 8000; int rr = id / 20, cc = id - rr * 20;
                       x = ((float)cc + 0.5f) * 32.f; y = ((float)rr + 0.5f) * 32.f; }
}

// Block-reduce a double (256 threads); result valid on thread 0.
__device__ __forceinline__ double block_red(double v, double* sred) {
  for (int off = 32; off > 0; off >>= 1) v += __shfl_down(v, off);
  int wid = threadIdx.x >> 6;
  if ((threadIdx.x & 63) == 0) sred[wid] = v;
  __syncthreads();
  double r = 0.0;
  if (threadIdx.x == 0) r = sred[0] + sred[1] + sred[2] + sred[3];
  __syncthreads();
  return r;
}

// conservative grid range for centers (c+0.5)*s inside (lo, hi)
__device__ __forceinline__ void grange(float lo, float hi, float s, int G,
                                       int& a0, int& an) {
  int c0 = max(0, (int)floorf(lo / s - 0.5f));
  int c1 = min(G - 1, (int)ceilf(hi / s - 0.5f));
  a0 = c0;
  an = max(0, c1 - c0 + 1);
}

// ---- Node 1: blocks 0..799 = wave-per-(b,n) topk (zero barriers);
// ----         blocks 800..  = background F-pass over ps (streaming).
__global__ __launch_bounds__(256) void combo_kernel(
    const float* __restrict__ ps, const float* __restrict__ pb,
    const int* __restrict__ gl, const float* __restrict__ gtb,
    int* __restrict__ topk_out, unsigned* __restrict__ maxm,
    unsigned* __restrict__ maxi, double* __restrict__ partF)
{
  __shared__ unsigned long long cand[4][MAXC];
  __shared__ int cnt[4];
  __shared__ double sred[4];

  if (blockIdx.x >= TK_BLOCKS) {
    // ---------------- F-pass: pure streaming background sum ----------------
    const int fb = blockIdx.x - TK_BLOCKS;
    const float4* ps4 = (const float4*)ps;
    double acc = 0.0;
    for (unsigned gid = (unsigned)fb * 256 + threadIdx.x; gid < TOTAL4;
         gid += (unsigned)F_BLOCKS * 256) {
      float4 s4 = ps4[gid];
      acc += (double)(fbg(s4.x) + fbg(s4.y) + fbg(s4.z) + fbg(s4.w));
    }
    double r = block_red(acc, sred);
    if (threadIdx.x == 0) partF[fb] = r;
    return;
  }

  // --------------------------- topk branch ---------------------------------
  const int wid = (int)(threadIdx.x >> 6);
  const int lane = (int)(threadIdx.x & 63);
  const int bn = blockIdx.x * 4 + wid;
  const int b = bn / NGT;
  const float gx1 = gtb[bn * 4 + 0], gy1 = gtb[bn * 4 + 1];
  const float gx2 = gtb[bn * 4 + 2], gy2 = gtb[bn * 4 + 3];
  const int cls = gl[bn];
  const float ga = clamp0(gx2 - gx1) * clamp0(gy2 - gy1);
  const float4* pbb = (const float4*)pb + (size_t)b * NL;
  const float* psb = ps + (size_t)b * NL * NC;

  if (lane == 0) {
    cnt[wid] = 0;
    maxm[bn] = 0u;   // replaces host-side memset (assign runs after us)
    maxi[bn] = 0u;
  }

  // Pass A: zero-metric mask for anchors 0..63 (row 0 of s8 grid), in-wave.
  unsigned long long zm;
  {
    const int l = lane;
    float4 p = pbb[l];
    float x = ((float)l + 0.5f) * 8.0f, y = 4.0f;
    float ox = fminf(p.z, gx2) - fmaxf(p.x, gx1);
    float oy = fminf(p.w, gy2) - fmaxf(p.y, gy1);
    float ov = clamp0(ox) * clamp0(oy);
    float pa = clamp0(p.z - p.x) * clamp0(p.w - p.y);
    float iou = ov * __builtin_amdgcn_rcpf(ga + pa - ov + 1e-9f);
    bool ins = fminf(fminf(x - gx1, y - gy1),
                     fminf(gx2 - x, gy2 - y)) > 1e-9f;
    bool pos = ins && (iou > 0.f);
    zm = __ballot(!pos);  // uniform across the wave
  }

  // Candidate windows per scale (identical scalars on all lanes).
  int c8, nc8, r8, nr8, c16, nc16, r16, nr16, c32, nc32, r32, nr32;
  grange(gx1, gx2, 8.f, 80, c8, nc8);   grange(gy1, gy2, 8.f, 80, r8, nr8);
  grange(gx1, gx2, 16.f, 40, c16, nc16); grange(gy1, gy2, 16.f, 40, r16, nr16);
  grange(gx1, gx2, 32.f, 20, c32, nc32); grange(gy1, gy2, 32.f, 20, r32, nr32);
  const int t8 = nc8 * nr8, t16 = nc16 * nr16, t32 = nc32 * nr32;
  const int total = t8 + t16 + t32;

  // Phase 1: test enumerated candidates; positives -> this wave's LDS list.
  for (int idx = lane; idx < total; idx += 64) {
    int l; float x, y;
    if (idx < t8) {
      int q = idx / nc8, cc = c8 + (idx - q * nc8), rr = r8 + q;
      l = rr * 80 + cc; x = ((float)cc + 0.5f) * 8.f; y = ((float)rr + 0.5f) * 8.f;
    } else if (idx < t8 + t16) {
      int id = idx - t8;
      int q = id / nc16, cc = c16 + (id - q * nc16), rr = r16 + q;
      l = 6400 + rr * 40 + cc; x = ((float)cc + 0.5f) * 16.f; y = ((float)rr + 0.5f) * 16.f;
    } else {
      int id = idx - t8 - t16;
      int q = id / nc32, cc = c32 + (id - q * nc32), rr = r32 + q;
      l = 8000 + rr * 20 + cc; x = ((float)cc + 0.5f) * 32.f; y = ((float)rr + 0.5f) * 32.f;
    }
    float4 p = pbb[l];
    float ox = fminf(p.z, gx2) - fmaxf(p.x, gx1);
    float oy = fminf(p.w, gy2) - fmaxf(p.y, gy1);
    float ov = clamp0(ox) * clamp0(oy);
    float pa = clamp0(p.z - p.x) * clamp0(p.w - p.y);
    float iou = ov * __builtin_amdgcn_rcpf(ga + pa - ov + 1e-9f);
    bool ins = fminf(fminf(x - gx1, y - gy1),
                     fminf(gx2 - x, gy2 - y)) > 1e-9f;
    if (ins && iou > 0.f) {
      int id2 = atomicAdd(&cnt[wid], 1);
      if (id2 < MAXC)
        cand[wid][id2] = ((unsigned long long)__float_as_uint(iou) << 32) |
                         (unsigned long long)(0xFFFFFFFFu - (unsigned)l);
    }
  }

  // Phase 2: gather score for positives; finalize key v = sc * iou^6.
  const int n = min(cnt[wid], MAXC);   // uniform per wave
  unsigned long long zadd = 0ull;
  for (int idx = lane; idx < n; idx += 64) {
    unsigned long long e = cand[wid][idx];
    unsigned lowk = (unsigned)e;
    int l = (int)(0xFFFFFFFFu - lowk);
    float iou = __uint_as_float((unsigned)(e >> 32));
    float sc = psb[(size_t)l * NC + cls];
    float i2 = iou * iou;
    float v = sc * i2 * i2 * i2;
    if (v > 0.f) {
      cand[wid][idx] = mkkey(v, lowk);
    } else {               // underflow: metric exactly 0 -> zero-tie set
      cand[wid][idx] = 0ull;
      if (l < 64) zadd |= (1ull << l);
    }
  }
  for (int off = 1; off < 64; off <<= 1)
    zadd |= __shfl_xor(zadd, off);
  zm |= zadd;              // still uniform

  // Merge: 13 rounds of pure-shuffle wave max; lanes hold <=10 candidates.
  unsigned long long c[MAXC / 64];
#pragma unroll
  for (int j = 0; j < MAXC / 64; ++j) {
    int idx = lane + 64 * j;
    c[j] = (idx < n) ? cand[wid][idx] : 0ull;
  }
  for (int k = 0; k < KTOP; ++k) {
    unsigned long long m = c[0];
#pragma unroll
    for (int j = 1; j < MAXC / 64; ++j) m = (c[j] > m) ? c[j] : m;
    for (int off = 1; off < 64; off <<= 1) {
      unsigned long long o = __shfl_xor(m, off);
      m = (o > m) ? o : m;
    }
    int outl;
    if (m != 0ull) {  // a positive candidate wins
#pragma unroll
      for (int j = 0; j < MAXC / 64; ++j)
        if (c[j] == m) c[j] = 0ull;
      outl = (int)(0xFFFFFFFFu - (unsigned)(m & 0xFFFFFFFFull));
    } else {          // pad with smallest-index zero-metric anchor
      outl = (int)(__ffsll((long long)zm) - 1);
      zm &= zm - 1;
    }
    if (lane == 0) topk_out[bn * KTOP + k] = outl;
  }
}

// ---- Node 2: bitmask-inverted assignment ----------------------------------
__global__ __launch_bounds__(256) void assign_kernel(
    const float* __restrict__ ps, const float* __restrict__ pb,
    const int* __restrict__ gl, const float* __restrict__ gtb,
    const float* __restrict__ pad, const int* __restrict__ topk,
    int* __restrict__ nstar, float* __restrict__ astar,
    unsigned* __restrict__ maxm, unsigned* __restrict__ maxi)
{
  __shared__ float4 sgt[NGT];
  __shared__ int sgl[NGT];
  __shared__ float spad[NGT];
  __shared__ unsigned hitm[256][4];   // 100-bit mask per anchor
  const int b = blockIdx.y;
  const int l0 = blockIdx.x * 256;

  for (int i = threadIdx.x; i < NGT; i += 256) {
    sgt[i] = ((const float4*)gtb)[b * NGT + i];
    sgl[i] = gl[b * NGT + i];
    spad[i] = pad[b * NGT + i];
  }
  hitm[threadIdx.x][0] = 0u; hitm[threadIdx.x][1] = 0u;
  hitm[threadIdx.x][2] = 0u; hitm[threadIdx.x][3] = 0u;
  __syncthreads();

  // Scatter: batch's 1300 topk entries -> hit bits for anchors in range.
  for (int i = threadIdx.x; i < NGT * KTOP; i += 256) {
    const int n = i / KTOP;
    if (spad[n] == 0.f) continue;
    const int l = topk[b * NGT * KTOP + i];
    if (l < l0 || l >= l0 + 256 || l >= NL) continue;
    float ax, ay;
    anchor_xy(l, ax, ay);
    float4 g = sgt[n];
    bool ins = fminf(fminf(ax - g.x, ay - g.y),
                     fminf(g.z - ax, g.w - ay)) > 1e-9f;
    if (ins) atomicOr(&hitm[l - l0][n >> 5], 1u << (n & 31));
  }
  __syncthreads();

  const int l = l0 + threadIdx.x;
  if (l >= NL) return;

  const unsigned m0 = hitm[threadIdx.x][0], m1 = hitm[threadIdx.x][1];
  const unsigned m2 = hitm[threadIdx.x][2], m3 = hitm[threadIdx.x][3];
  const int mps = __popc(m0) + __popc(m1) + __popc(m2) + __popc(m3);

  int ns = -1;
  float iou_s = 0.f, al_s = 0.f;
  if (mps > 0) {
    float4 p = ((const float4*)pb)[(size_t)b * NL + l];
    float pa = clamp0(p.z - p.x) * clamp0(p.w - p.y);
    if (mps == 1) {
      if (m0) ns = __ffs(m0) - 1;
      else if (m1) ns = 32 + __ffs(m1) - 1;
      else if (m2) ns = 64 + __ffs(m2) - 1;
      else ns = 96 + __ffs(m3) - 1;
      float4 g = sgt[ns];
      float ox = fminf(p.z, g.z) - fmaxf(p.x, g.x);
      float oy = fminf(p.w, g.w) - fmaxf(p.y, g.y);
      float ov = clamp0(ox) * clamp0(oy);
      float ga = clamp0(g.z - g.x) * clamp0(g.w - g.y);
      iou_s = ov / (ga + pa - ov + 1e-9f);   // exact: matches original
    } else {
      // is_max_iou replacement: argmax over ALL n (incl. pad), first-max wins
      int max_n = 0; float max_iou = -1.f;
      for (int n = 0; n < NGT; ++n) {
        float4 g = sgt[n];
        float ox = fminf(p.z, g.z) - fmaxf(p.x, g.x);
        float oy = fminf(p.w, g.w) - fmaxf(p.y, g.y);
        float ov = clamp0(ox) * clamp0(oy);
        float ga = clamp0(g.z - g.x) * clamp0(g.w - g.y);
        float iou = ov / (ga + pa - ov + 1e-9f);
        if (iou > max_iou) { max_iou = iou; max_n = n; }
      }
      ns = max_n; iou_s = max_iou;
    }
    float sc = ps[((size_t)b * NL + l) * NC + sgl[ns]];
    float i2 = iou_s * iou_s;
    al_s = sc * i2 * i2 * i2;
    atomicMax(&maxm[b * NGT + ns], __float_as_uint(al_s));
    atomicMax(&maxi[b * NGT + ns], __float_as_uint(iou_s));
  }
  nstar[b * NL + l] = ns;
  astar[b * NL + l] = al_s;
}

// --- Node 3: per-row correction: term_j - f(s_j) + GIoU + scale-sum --------
__global__ __launch_bounds__(256) void correct_kernel(
    const float* __restrict__ ps, const float* __restrict__ pb,
    const float* __restrict__ gtb, const int* __restrict__ gl,
    const int* __restrict__ nstar, const float* __restrict__ astar,
    const unsigned* __restrict__ maxm, const unsigned* __restrict__ maxi,
    double* __restrict__ partC)
{
  __shared__ double sred[4];
  const int row = blockIdx.x * 256 + threadIdx.x;
  const int b = row / NL;
  double csum = 0.0, gsum = 0.0, asum = 0.0;
  int ns = nstar[row];
  if (ns >= 0) {
    float mm = __uint_as_float(maxm[b * NGT + ns]);
    float mi = __uint_as_float(maxi[b * NGT + ns]);
    float scale = astar[row] / (mm + 1e-9f) * mi;
    int j = gl[b * NGT + ns];
    asum = (double)scale;
    // class-loss correction at the assigned class
    float s = ps[(size_t)row * NC + j];
    float pcl = fminf(fmaxf(s, 1e-9f), 1.f - 1e-9f);
    float lp1 = __log2f(1.f - pcl) * LN2F;
    float lpp = __log2f(pcl) * LN2F;
    float term = -(scale * lpp + (1.f - scale) * lp1) * scale;
    float fsj = -lp1 * 0.75f * s * s;
    csum = (double)(term - fsj);
    // GIoU
    float4 p = ((const float4*)pb)[row];
    float4 g = ((const float4*)gtb)[b * NGT + ns];
    float x1 = fmaxf(p.x, g.x), y1 = fmaxf(p.y, g.y);
    float x2 = fminf(p.z, g.z), y2 = fminf(p.w, g.w);
    float ov = clamp0(x2 - x1) * clamp0(y2 - y1);
    float pa = clamp0(p.z - p.x) * clamp0(p.w - p.y);
    float ga = clamp0(g.z - g.x) * clamp0(g.w - g.y);
    float un = pa + ga - ov + 1e-10f;
    float iou = ov / un;
    float cx1 = fminf(p.x, g.x), cy1 = fminf(p.y, g.y);
    float cx2 = fmaxf(p.z, g.z), cy2 = fmaxf(p.w, g.w);
    float cc = clamp0(cx2 - cx1) * clamp0(cy2 - cy1) + 1e-10f;
    float gi = 1.f - (iou - (cc - un) / cc);
    gsum = (double)(gi * scale);
  }
  double r0 = block_red(csum, sred);
  double r1 = block_red(gsum, sred);
  double r2 = block_red(asum, sred);
  if (threadIdx.x == 0) {
    partC[(size_t)blockIdx.x * 4 + 0] = r0;
    partC[(size_t)blockIdx.x * 4 + 1] = r1;
    partC[(size_t)blockIdx.x * 4 + 2] = r2;
  }
}

// ---------------- Node 4: reduce partials, emit scalar ---------------------
__global__ __launch_bounds__(256) void fin_kernel(
    const double* __restrict__ partF, const double* __restrict__ partC,
    float* __restrict__ out)
{
  __shared__ double sred[4];
  double c = 0.0, g = 0.0, a = 0.0;
  for (int i = threadIdx.x; i < F_BLOCKS; i += 256) c += partF[i];
  for (int i = threadIdx.x; i < CR_BLOCKS; i += 256) {
    c += partC[(size_t)i * 4 + 0];
    g += partC[(size_t)i * 4 + 1];
    a += partC[(size_t)i * 4 + 2];
  }
  c = block_red(c, sred);
  g = block_red(g, sred);
  a = block_red(a, sred);
  if (threadIdx.x == 0) {
    double s = a > 1.0 ? a : 1.0;
    out[0] = (float)((c + 2.5 * g) / s);
  }
}

// ---------------------------------------------------------------------------
extern "C" void kernel_launch(void* const* d_in, const int* in_sizes, int n_in,
                              void* d_out, int out_size, void* d_ws, size_t ws_size,
                              hipStream_t stream) {
  const float* ps  = (const float*)d_in[0];   // [32,8400,80]
  const float* pbx = (const float*)d_in[1];   // [32,8400,4]
  const float* ap  = (const float*)d_in[2];   // [8400,2] (unused: grid math)
  const int*   gl  = (const int*)d_in[3];     // [32,100,1]
  const float* gtb = (const float*)d_in[4];   // [32,100,4]
  const float* pad = (const float*)d_in[5];   // [32,100,1]
  (void)ap;

  char* ws = (char*)d_ws;
  const size_t OFF_MAXM  = 0;                                 // 3200 u32
  const size_t OFF_MAXI  = OFF_MAXM + 4ul * NB * NGT;         // 3200 u32
  const size_t OFF_TOPK  = OFF_MAXI + 4ul * NB * NGT;         // 41600 i32
  const size_t OFF_NSTAR = OFF_TOPK + 4ul * NB * NGT * KTOP;  // 268800 i32
  const size_t OFF_ASTAR = OFF_NSTAR + 4ul * NB * NL;         // 268800 f32
  const size_t OFF_PARTF = OFF_ASTAR + 4ul * NB * NL;         // 2048 f64
  const size_t OFF_PARTC = OFF_PARTF + 8ul * F_BLOCKS;        // 1050*4 f64

  unsigned* maxm  = (unsigned*)(ws + OFF_MAXM);
  unsigned* maxi  = (unsigned*)(ws + OFF_MAXI);
  int*      topk  = (int*)(ws + OFF_TOPK);
  int*      nstar = (int*)(ws + OFF_NSTAR);
  float*    astar = (float*)(ws + OFF_ASTAR);
  double*   partF = (double*)(ws + OFF_PARTF);
  double*   partC = (double*)(ws + OFF_PARTC);

  // No memset nodes: combo (topk branch) zeroes maxm/maxi in-kernel.

  hipLaunchKernelGGL(combo_kernel, dim3(TK_BLOCKS + F_BLOCKS), dim3(256), 0,
                     stream, ps, pbx, gl, gtb, topk, maxm, maxi, partF);
  hipLaunchKernelGGL(assign_kernel, dim3(SC_BLOCKS_X, NB), dim3(256), 0, stream,
                     ps, pbx, gl, gtb, pad, topk, nstar, astar, maxm, maxi);
  hipLaunchKernelGGL(correct_kernel, dim3(CR_BLOCKS), dim3(256), 0, stream,
                     ps, pbx, gtb, gl, nstar, astar, maxm, maxi, partC);
  hipLaunchKernelGGL(fin_kernel, dim3(1), dim3(256), 0, stream, partF, partC,
                     (float*)d_out);
}